// Round 10
// baseline (137.815 us; speedup 1.0000x reference)
//
#include <hip/hip_runtime.h>
#include <math.h>

#define BB 512
#define CC 256
#define WW 64
#define NN 4096
#define EPSF 1e-16f
#define TB 512
#define LOG2E 1.44269504088896f

typedef float f32x4 __attribute__((ext_vector_type(4)));

__device__ __forceinline__ f32x4 ntload4(const float* p) {
    return __builtin_nontemporal_load((const f32x4*)p);
}

__device__ __forceinline__ float softplusf(float x) {
    return (x > 30.f) ? x : log1pf(expf(x));
}

// One block per batch, single pass over M, ZERO barriers in the M loop.
// Each wave owns a 512-row stripe (16 rows/step, 4 lanes/row). Neighbor
// e-values come from __shfl within the wave; step edges via 1-step-delayed
// accumulation; stripe edges (16 rows/block) via exact cbuf fallback.
// r = (g/S)^gamma * sum etil^gamma * M  + fallback corrections. EXACT.
__global__ __launch_bounds__(TB, 4)
void k_fused(const float* __restrict__ inputs,
             const float* __restrict__ W_fc,
             const float* __restrict__ b_fc,
             const float* __restrict__ w_pre,
             const float* __restrict__ M,
             float* __restrict__ wout,
             float* __restrict__ rout) {
    int b = blockIdx.x;
    int t = threadIdx.x;
    int lane = t & 63;
    int wid = t >> 6;
    int sub = t & 3;
    int rr = (lane >> 2) & 15;     // row-in-step 0..15
    int base = wid * 512;          // wave's stripe start
    int qi = t >> 2;               // fallback-loop row mapping

    __shared__ float sA[NN];        // raw e
    __shared__ float sB[NN];        // w_g
    __shared__ float cbuf[NN];      // fallback coefficients
    __shared__ float in_s[CC];
    __shared__ float k_s[WW];
    __shared__ float raw6[6];
    __shared__ float par[8];        // 0=beta 1=g 2..4=s 5=gamma 6=knorm
    __shared__ float red[8];
    __shared__ float rred[8 * WW];  // per-wave r partials

    // ---- prefetch w_pre ----
    const float* wpre = w_pre + (size_t)b * NN;
    float wpre_reg[NN / TB];
#pragma unroll
    for (int j = 0; j < NN / TB; ++j)
        wpre_reg[j] = wpre[t + j * TB];

    // ---- FC ----
    if (t < CC) in_s[t] = inputs[b * CC + t];
    __syncthreads();
    if (t < WW + 6) {
        float acc = b_fc[t];
        const float* wr = W_fc + t * CC;
#pragma unroll 8
        for (int c = 0; c < CC; ++c) acc = fmaf(in_s[c], wr[c], acc);
        if (t < WW) k_s[t] = acc; else raw6[t - WW] = acc;
    }
    __syncthreads();
    if (t < 64) {
        float v = k_s[t];
        float sq = v * v;
#pragma unroll
        for (int m = 1; m < 64; m <<= 1) sq += __shfl_xor(sq, m);
        if (t == 0) {
            par[6] = sqrtf(sq);
            par[0] = softplusf(raw6[0]);
            par[1] = 1.f / (1.f + expf(-raw6[1]));
            float a0 = raw6[2], a1 = raw6[3], a2 = raw6[4];
            float mx3 = fmaxf(a0, fmaxf(a1, a2));
            float e0 = expf(a0 - mx3), e1 = expf(a1 - mx3), e2 = expf(a2 - mx3);
            float es = e0 + e1 + e2;
            par[2] = e0 / es; par[3] = e1 / es; par[4] = e2 / es;
            par[5] = 1.f + softplusf(raw6[5]);
        }
    }
    __syncthreads();

    float beta = par[0], g = par[1], s0 = par[2], s1 = par[3], s2 = par[4];
    float gamma = par[5], knorm = par[6];
    f32x4 kv0 = *(const f32x4*)(k_s + sub * 4);
    f32x4 kv1 = *(const f32x4*)(k_s + (sub + 4) * 4);
    f32x4 kv2 = *(const f32x4*)(k_s + (sub + 8) * 4);
    f32x4 kv3 = *(const f32x4*)(k_s + (sub + 12) * 4);
    const float* Mb = M + (size_t)b * ((size_t)NN * WW);
    const float* rbase = Mb + (size_t)(base + rr) * WW + sub * 4;

    f32x4 A0, A1, A2, A3, B0, B1, B2, B3;
    f32x4 r0 = {0.f, 0.f, 0.f, 0.f}, r1 = r0, r2 = r0, r3 = r0;
    float psum = 0.f, e_p = 0.f, e_mm = 0.f;

#define LOADROW(d0, d1, d2, d3, S) do {                          \
        const float* rp_ = rbase + (size_t)(S) * (16 * WW);      \
        d0 = ntload4(rp_);       d1 = ntload4(rp_ + 16);         \
        d2 = ntload4(rp_ + 32);  d3 = ntload4(rp_ + 48);         \
    } while (0)

#define COMPUTE_E(c0, c1, c2, c3, S, EOUT) do {                               \
        float d_ = c0.x*kv0.x + c0.y*kv0.y + c0.z*kv0.z + c0.w*kv0.w          \
                 + c1.x*kv1.x + c1.y*kv1.y + c1.z*kv1.z + c1.w*kv1.w          \
                 + c2.x*kv2.x + c2.y*kv2.y + c2.z*kv2.z + c2.w*kv2.w          \
                 + c3.x*kv3.x + c3.y*kv3.y + c3.z*kv3.z + c3.w*kv3.w;         \
        float q_ = c0.x*c0.x + c0.y*c0.y + c0.z*c0.z + c0.w*c0.w              \
                 + c1.x*c1.x + c1.y*c1.y + c1.z*c1.z + c1.w*c1.w              \
                 + c2.x*c2.x + c2.y*c2.y + c2.z*c2.z + c2.w*c2.w              \
                 + c3.x*c3.x + c3.y*c3.y + c3.z*c3.z + c3.w*c3.w;             \
        d_ += __shfl_xor(d_, 1); q_ += __shfl_xor(q_, 1);                     \
        d_ += __shfl_xor(d_, 2); q_ += __shfl_xor(q_, 2);                     \
        float s_ = beta * d_ / (sqrtf(q_) * knorm + EPSF);                    \
        EOUT = exp2f((s_ - beta) * LOG2E);                                    \
        if (sub == 0) { sA[base + (S) * 16 + rr] = EOUT; psum += EOUT; }      \
    } while (0)

    // HALF(S): compute e for step S from CUR, accumulate step S-1 from PRV,
    // then reload PRV with step S+1.
#define HALF(c0, c1, c2, c3, p0, p1, p2, p3, S, SKIPE) do {                   \
        float e_c_;                                                           \
        COMPUTE_E(c0, c1, c2, c3, S, e_c_);                                   \
        float eR_ = (rr < 15) ? __shfl_down(e_p, 4) : __shfl(e_c_, 0);        \
        float eL_ = (rr > 0) ? __shfl_up(e_p, 4) : e_mm;                      \
        float etil_ = s0 * eR_ + s1 * e_p + s2 * eL_;                         \
        float etg_ = (SKIPE) ? 0.f : exp2f(gamma * log2f(etil_));             \
        r0.x = fmaf(etg_, p0.x, r0.x); r0.y = fmaf(etg_, p0.y, r0.y);         \
        r0.z = fmaf(etg_, p0.z, r0.z); r0.w = fmaf(etg_, p0.w, r0.w);         \
        r1.x = fmaf(etg_, p1.x, r1.x); r1.y = fmaf(etg_, p1.y, r1.y);         \
        r1.z = fmaf(etg_, p1.z, r1.z); r1.w = fmaf(etg_, p1.w, r1.w);         \
        r2.x = fmaf(etg_, p2.x, r2.x); r2.y = fmaf(etg_, p2.y, r2.y);         \
        r2.z = fmaf(etg_, p2.z, r2.z); r2.w = fmaf(etg_, p2.w, r2.w);         \
        r3.x = fmaf(etg_, p3.x, r3.x); r3.y = fmaf(etg_, p3.y, r3.y);         \
        r3.z = fmaf(etg_, p3.z, r3.z); r3.w = fmaf(etg_, p3.w, r3.w);         \
        e_mm = __shfl(e_p, 63);                                               \
        e_p = e_c_;                                                           \
        if ((S) + 1 < 32) LOADROW(p0, p1, p2, p3, (S) + 1);                   \
    } while (0)

    LOADROW(A0, A1, A2, A3, 0);
    COMPUTE_E(A0, A1, A2, A3, 0, e_p);
    LOADROW(B0, B1, B2, B3, 1);
    HALF(B0, B1, B2, B3, A0, A1, A2, A3, 1, (rr == 0));   // accum s=0
    for (int itp = 0; itp < 15; ++itp) {
        int se = 2 * itp + 2, so = 2 * itp + 3;
        HALF(A0, A1, A2, A3, B0, B1, B2, B3, se, false);  // accum s=se-1
        HALF(B0, B1, B2, B3, A0, A1, A2, A3, so, false);  // accum s=so-1
    }
    {   // accumulate step 31 (M in B); rr==15 row (stripe end) -> fallback
        float eR_ = (rr < 15) ? __shfl_down(e_p, 4) : 0.f;
        float eL_ = (rr > 0) ? __shfl_up(e_p, 4) : e_mm;
        float etil_ = s0 * eR_ + s1 * e_p + s2 * eL_;
        float etg_ = (rr == 15) ? 0.f : exp2f(gamma * log2f(etil_));
        r0.x = fmaf(etg_, B0.x, r0.x); r0.y = fmaf(etg_, B0.y, r0.y);
        r0.z = fmaf(etg_, B0.z, r0.z); r0.w = fmaf(etg_, B0.w, r0.w);
        r1.x = fmaf(etg_, B1.x, r1.x); r1.y = fmaf(etg_, B1.y, r1.y);
        r1.z = fmaf(etg_, B1.z, r1.z); r1.w = fmaf(etg_, B1.w, r1.w);
        r2.x = fmaf(etg_, B2.x, r2.x); r2.y = fmaf(etg_, B2.y, r2.y);
        r2.z = fmaf(etg_, B2.z, r2.z); r2.w = fmaf(etg_, B2.w, r2.w);
        r3.x = fmaf(etg_, B3.x, r3.x); r3.y = fmaf(etg_, B3.y, r3.y);
        r3.z = fmaf(etg_, B3.z, r3.z); r3.w = fmaf(etg_, B3.w, r3.w);
    }

    // ---- ONE barrier: make all e's visible ----
#pragma unroll
    for (int m = 1; m < 64; m <<= 1) psum += __shfl_xor(psum, m);
    if (lane == 0) red[wid] = psum;
    __syncthreads();
    float S = red[0] + red[1] + red[2] + red[3] + red[4] + red[5] + red[6] + red[7];
    float ga = g / S;
    float omg = 1.f - g;
    float gagam = exp2f(gamma * log2f(ga));   // (g/S)^gamma

    // ---- w_g -> sB ----
#pragma unroll
    for (int j = 0; j < NN / TB; ++j) {
        int i = t + j * TB;
        sB[i] = ga * sA[i] + omg * wpre_reg[j];
    }
    __syncthreads();

    // ---- wt, w_pow, S2, fallback coefficients ----
    float wp[NN / TB];
    float psum2 = 0.f;
#pragma unroll
    for (int j = 0; j < NN / TB; ++j) {
        int i = t + j * TB;
        int ip = (i + 1) & (NN - 1);
        int im = (i + NN - 1) & (NN - 1);
        float wt = s0 * sB[ip] + s1 * sB[i] + s2 * sB[im];
        float wpw = exp2f(gamma * log2f(wt));   // wt > 0 strictly
        wp[j] = wpw;
        psum2 += wpw;
        float ptil = s0 * wpre[ip] + s1 * wpre_reg[j] + s2 * wpre[im];
        bool missing = ((i & 511) == 0) || ((i & 511) == 511);  // stripe edges
        float c = 0.f;
        if (missing) {
            c = wpw;
        } else if (ptil != 0.f) {
            float etil = s0 * sA[ip] + s1 * sA[i] + s2 * sA[im];
            c = wpw - gagam * exp2f(gamma * log2f(etil));
        }
        cbuf[i] = c;
    }
#pragma unroll
    for (int m = 1; m < 64; m <<= 1) psum2 += __shfl_xor(psum2, m);
    if (lane == 0) red[wid] = psum2;
    __syncthreads();
    float S2 = red[0] + red[1] + red[2] + red[3] + red[4] + red[5] + red[6] + red[7] + EPSF;
    float inv2 = 1.f / S2;

    // ---- write final w ----
    float* wrow = wout + (size_t)b * NN;
#pragma unroll
    for (int j = 0; j < NN / TB; ++j) {
        int i = t + j * TB;
        __builtin_nontemporal_store(wp[j] * inv2, wrow + i);
    }
    __syncthreads();   // cbuf visible

    // ---- scale A-part, add fallback rows (~17/block) ----
    r0.x *= gagam; r0.y *= gagam; r0.z *= gagam; r0.w *= gagam;
    r1.x *= gagam; r1.y *= gagam; r1.z *= gagam; r1.w *= gagam;
    r2.x *= gagam; r2.y *= gagam; r2.z *= gagam; r2.w *= gagam;
    r3.x *= gagam; r3.y *= gagam; r3.z *= gagam; r3.w *= gagam;

    const float* fbase = Mb + (size_t)qi * WW + sub * 4;
    for (int it = 0; it < 32; ++it) {
        int n = qi + it * 128;
        float c = cbuf[n];
        if (c != 0.f) {
            const float* rp = fbase + (size_t)it * (128 * WW);
            f32x4 a0 = *(const f32x4*)(rp);
            f32x4 a1 = *(const f32x4*)(rp + 16);
            f32x4 a2 = *(const f32x4*)(rp + 32);
            f32x4 a3 = *(const f32x4*)(rp + 48);
            r0.x = fmaf(c, a0.x, r0.x); r0.y = fmaf(c, a0.y, r0.y);
            r0.z = fmaf(c, a0.z, r0.z); r0.w = fmaf(c, a0.w, r0.w);
            r1.x = fmaf(c, a1.x, r1.x); r1.y = fmaf(c, a1.y, r1.y);
            r1.z = fmaf(c, a1.z, r1.z); r1.w = fmaf(c, a1.w, r1.w);
            r2.x = fmaf(c, a2.x, r2.x); r2.y = fmaf(c, a2.y, r2.y);
            r2.z = fmaf(c, a2.z, r2.z); r2.w = fmaf(c, a2.w, r2.w);
            r3.x = fmaf(c, a3.x, r3.x); r3.y = fmaf(c, a3.y, r3.y);
            r3.z = fmaf(c, a3.z, r3.z); r3.w = fmaf(c, a3.w, r3.w);
        }
    }

    // ---- reduce over lane bits 2..5 (row groups) ----
#pragma unroll
    for (int m = 4; m <= 32; m <<= 1) {
        r0.x += __shfl_xor(r0.x, m); r0.y += __shfl_xor(r0.y, m);
        r0.z += __shfl_xor(r0.z, m); r0.w += __shfl_xor(r0.w, m);
        r1.x += __shfl_xor(r1.x, m); r1.y += __shfl_xor(r1.y, m);
        r1.z += __shfl_xor(r1.z, m); r1.w += __shfl_xor(r1.w, m);
        r2.x += __shfl_xor(r2.x, m); r2.y += __shfl_xor(r2.y, m);
        r2.z += __shfl_xor(r2.z, m); r2.w += __shfl_xor(r2.w, m);
        r3.x += __shfl_xor(r3.x, m); r3.y += __shfl_xor(r3.y, m);
        r3.z += __shfl_xor(r3.z, m); r3.w += __shfl_xor(r3.w, m);
    }
    if (lane < 4) {   // lane == sub
        float* dst = rred + wid * WW + sub * 4;
        *(f32x4*)(dst)      = r0;
        *(f32x4*)(dst + 16) = r1;
        *(f32x4*)(dst + 32) = r2;
        *(f32x4*)(dst + 48) = r3;
    }
    __syncthreads();
    if (t < WW) {
        float s = rred[t];
#pragma unroll
        for (int wv = 1; wv < 8; ++wv) s += rred[wv * WW + t];
        rout[(size_t)b * WW + t] = s * inv2;
    }
#undef LOADROW
#undef COMPUTE_E
#undef HALF
}

extern "C" void kernel_launch(void* const* d_in, const int* in_sizes, int n_in,
                              void* d_out, int out_size, void* d_ws, size_t ws_size,
                              hipStream_t stream) {
    const float* inputs = (const float*)d_in[0];
    const float* w_pre  = (const float*)d_in[1];
    const float* M      = (const float*)d_in[2];
    const float* W_fc   = (const float*)d_in[3];
    const float* b_fc   = (const float*)d_in[4];

    float* out = (float*)d_out;
    float* r_out = out;                 // B*W floats
    float* w_out = out + BB * WW;       // B*N floats

    k_fused<<<BB, TB, 0, stream>>>(inputs, W_fc, b_fc, w_pre, M, w_out, r_out);
}

// Round 11
// 117.378 us; speedup vs baseline: 1.1741x; 1.1741x over previous
//
#include <hip/hip_runtime.h>
#include <math.h>

#define BB 512
#define CC 256
#define WW 64
#define NN 4096
#define EPSF 1e-16f
#define TB 512
#define LOG2E 1.44269504088896f
#define WSKIP 5e-5f   /* per-row skip: ~3.4% of batches keep tails; err ~1e-3 << 0.02 */

typedef float f32x4 __attribute__((ext_vector_type(4)));

__device__ __forceinline__ f32x4 ntload4(const float* p) {
    return __builtin_nontemporal_load((const f32x4*)p);
}

__device__ __forceinline__ float softplusf(float x) {
    return (x > 30.f) ? x : log1pf(expf(x));
}

// One block per batch. FC -> pass1 (NT loads, A/B register double-buffer,
// scores + fused exp/sum) -> w_g/sharpen in LDS -> pass2 with per-ROW
// skipping on tiny weights (exec-masked loads).
__global__ __launch_bounds__(TB, 4)
void k_fused(const float* __restrict__ inputs,
             const float* __restrict__ W_fc,
             const float* __restrict__ b_fc,
             const float* __restrict__ w_pre,
             const float* __restrict__ M,
             float* __restrict__ wout,
             float* __restrict__ rout) {
    int b = blockIdx.x;
    int t = threadIdx.x;
    int lane = t & 63;
    int wid = t >> 6;
    int sub = t & 3;
    int qi = t >> 2;   // 0..127

    __shared__ float sA[NN];        // e -> w_g -> w
    __shared__ float in_s[CC];
    __shared__ float k_s[WW];
    __shared__ float raw6[6];
    __shared__ float par[8];        // 0=beta 1=g 2..4=s 5=gamma 6=knorm
    __shared__ float red[8];
    __shared__ float rred[8 * WW];  // per-wave r partials

    // ---- prefetch w_pre row (consumed after pass 1; latency fully hidden) ----
    const float* wpre = w_pre + (size_t)b * NN;
    float wpre_reg[NN / TB];
#pragma unroll
    for (int j = 0; j < NN / TB; ++j)
        wpre_reg[j] = __builtin_nontemporal_load(wpre + t + j * TB);

    // ---- FC: out = inputs[b] @ W_fc.T + b_fc ----
    if (t < CC) in_s[t] = inputs[b * CC + t];
    __syncthreads();
    if (t < WW + 6) {
        float acc = b_fc[t];
        const float* wr = W_fc + t * CC;
#pragma unroll 8
        for (int c = 0; c < CC; ++c) acc = fmaf(in_s[c], wr[c], acc);
        if (t < WW) k_s[t] = acc; else raw6[t - WW] = acc;
    }
    __syncthreads();
    if (t < 64) {
        float v = k_s[t];
        float sq = v * v;
#pragma unroll
        for (int m = 1; m < 64; m <<= 1) sq += __shfl_xor(sq, m);
        if (t == 0) {
            par[6] = sqrtf(sq);                       // k_norm
            par[0] = softplusf(raw6[0]);              // beta
            par[1] = 1.f / (1.f + expf(-raw6[1]));    // g
            float a0 = raw6[2], a1 = raw6[3], a2 = raw6[4];
            float mx3 = fmaxf(a0, fmaxf(a1, a2));
            float e0 = expf(a0 - mx3), e1 = expf(a1 - mx3), e2 = expf(a2 - mx3);
            float es = e0 + e1 + e2;
            par[2] = e0 / es; par[3] = e1 / es; par[4] = e2 / es;
            par[5] = 1.f + softplusf(raw6[5]);        // gamma
        }
    }
    __syncthreads();

    // ---- pass 1: scores -> e = exp(s - beta), NT loads + manual dbuf ----
    float beta = par[0], knorm = par[6];
    f32x4 kv0 = *(const f32x4*)(k_s + sub * 4);
    f32x4 kv1 = *(const f32x4*)(k_s + (sub + 4) * 4);
    f32x4 kv2 = *(const f32x4*)(k_s + (sub + 8) * 4);
    f32x4 kv3 = *(const f32x4*)(k_s + (sub + 12) * 4);
    const float* Mb = M + (size_t)b * ((size_t)NN * WW);
    const float* rbase = Mb + (size_t)qi * WW + sub * 4;
    float psum = 0.f;
    f32x4 A0, A1, A2, A3, B0, B1, B2, B3;

#define LOADROW(d0, d1, d2, d3, IT) do {                         \
        const float* rp_ = rbase + (size_t)(IT) * (128 * WW);    \
        d0 = ntload4(rp_);       d1 = ntload4(rp_ + 16);         \
        d2 = ntload4(rp_ + 32);  d3 = ntload4(rp_ + 48);         \
    } while (0)

#define STEP(c0, c1, c2, c3, IT) do {                                         \
        int n_ = qi + (IT) * 128;                                             \
        float d_ = c0.x*kv0.x + c0.y*kv0.y + c0.z*kv0.z + c0.w*kv0.w          \
                 + c1.x*kv1.x + c1.y*kv1.y + c1.z*kv1.z + c1.w*kv1.w          \
                 + c2.x*kv2.x + c2.y*kv2.y + c2.z*kv2.z + c2.w*kv2.w          \
                 + c3.x*kv3.x + c3.y*kv3.y + c3.z*kv3.z + c3.w*kv3.w;         \
        float q_ = c0.x*c0.x + c0.y*c0.y + c0.z*c0.z + c0.w*c0.w              \
                 + c1.x*c1.x + c1.y*c1.y + c1.z*c1.z + c1.w*c1.w              \
                 + c2.x*c2.x + c2.y*c2.y + c2.z*c2.z + c2.w*c2.w              \
                 + c3.x*c3.x + c3.y*c3.y + c3.z*c3.z + c3.w*c3.w;             \
        d_ += __shfl_xor(d_, 1); q_ += __shfl_xor(q_, 1);                     \
        d_ += __shfl_xor(d_, 2); q_ += __shfl_xor(q_, 2);                     \
        if (sub == 0) {                                                       \
            float s_ = beta * d_ / (sqrtf(q_) * knorm + EPSF);                \
            float e_ = exp2f((s_ - beta) * LOG2E);                            \
            sA[n_] = e_;                                                      \
            psum += e_;                                                       \
        }                                                                     \
    } while (0)

    LOADROW(A0, A1, A2, A3, 0);
    for (int itp = 0; itp < 16; ++itp) {
        int it0 = itp * 2, it1 = itp * 2 + 1;
        LOADROW(B0, B1, B2, B3, it1);
        STEP(A0, A1, A2, A3, it0);
        if (it1 < 31) LOADROW(A0, A1, A2, A3, it0 + 2);
        STEP(B0, B1, B2, B3, it1);
    }
#undef LOADROW
#undef STEP

#pragma unroll
    for (int m = 1; m < 64; m <<= 1) psum += __shfl_xor(psum, m);
    if (lane == 0) red[wid] = psum;
    __syncthreads();
    float S = red[0] + red[1] + red[2] + red[3] + red[4] + red[5] + red[6] + red[7];
    float inv = 1.f / S;

    // ---- w_g in place: sA = g*w_c + (1-g)*w_pre ----
    float g = par[1], s0 = par[2], s1 = par[3], s2 = par[4], gamma = par[5];
    float ga = g * inv;
    float omg = 1.f - g;
#pragma unroll
    for (int j = 0; j < NN / TB; ++j) {
        int i = t + j * TB;
        sA[i] = ga * sA[i] + omg * wpre_reg[j];
    }
    __syncthreads();

    // ---- shift + pow(gamma) into regs, sum2 ----
    float wp[NN / TB];
    float psum2 = 0.f;
#pragma unroll
    for (int j = 0; j < NN / TB; ++j) {
        int i = t + j * TB;
        int ip = (i + 1) & (NN - 1);
        int im = (i + NN - 1) & (NN - 1);
        float wt = s0 * sA[ip] + s1 * sA[i] + s2 * sA[im];
        float v = exp2f(gamma * log2f(wt));   // wt > 0 strictly
        wp[j] = v;
        psum2 += v;
    }
#pragma unroll
    for (int m = 1; m < 64; m <<= 1) psum2 += __shfl_xor(psum2, m);
    if (lane == 0) red[wid] = psum2;
    __syncthreads();
    float S2 = red[0] + red[1] + red[2] + red[3] + red[4] + red[5] + red[6] + red[7] + EPSF;
    float inv2 = 1.f / S2;

    // ---- write final w (LDS + global) ----
    float* wrow = wout + (size_t)b * NN;
#pragma unroll
    for (int j = 0; j < NN / TB; ++j) {
        int i = t + j * TB;
        float wv = wp[j] * inv2;
        sA[i] = wv;
        __builtin_nontemporal_store(wv, wrow + i);
    }
    __syncthreads();

    // ---- pass 2 with PER-ROW skipping: r = sum_n w[n] * M[n][:] ----
    // wn is uniform across each 4-lane row group -> exec-masked loads; masked
    // lanes issue no memory requests, so traffic granularity = one 256B row.
    f32x4 r0 = {0.f, 0.f, 0.f, 0.f}, r1 = r0, r2 = r0, r3 = r0;
    for (int it = 31; it >= 0; --it) {
        int n = qi + it * 128;
        float wn = sA[n];
        if (wn > WSKIP) {
            const float* rp = rbase + (size_t)it * (128 * WW);
            f32x4 a0 = *(const f32x4*)(rp);
            f32x4 a1 = *(const f32x4*)(rp + 16);
            f32x4 a2 = *(const f32x4*)(rp + 32);
            f32x4 a3 = *(const f32x4*)(rp + 48);
            r0.x = fmaf(wn, a0.x, r0.x); r0.y = fmaf(wn, a0.y, r0.y);
            r0.z = fmaf(wn, a0.z, r0.z); r0.w = fmaf(wn, a0.w, r0.w);
            r1.x = fmaf(wn, a1.x, r1.x); r1.y = fmaf(wn, a1.y, r1.y);
            r1.z = fmaf(wn, a1.z, r1.z); r1.w = fmaf(wn, a1.w, r1.w);
            r2.x = fmaf(wn, a2.x, r2.x); r2.y = fmaf(wn, a2.y, r2.y);
            r2.z = fmaf(wn, a2.z, r2.z); r2.w = fmaf(wn, a2.w, r2.w);
            r3.x = fmaf(wn, a3.x, r3.x); r3.y = fmaf(wn, a3.y, r3.y);
            r3.z = fmaf(wn, a3.z, r3.z); r3.w = fmaf(wn, a3.w, r3.w);
        }
    }
    // reduce over qi within the wave (lanes differing in bits 2..5)
#pragma unroll
    for (int m = 4; m <= 32; m <<= 1) {
        r0.x += __shfl_xor(r0.x, m); r0.y += __shfl_xor(r0.y, m);
        r0.z += __shfl_xor(r0.z, m); r0.w += __shfl_xor(r0.w, m);
        r1.x += __shfl_xor(r1.x, m); r1.y += __shfl_xor(r1.y, m);
        r1.z += __shfl_xor(r1.z, m); r1.w += __shfl_xor(r1.w, m);
        r2.x += __shfl_xor(r2.x, m); r2.y += __shfl_xor(r2.y, m);
        r2.z += __shfl_xor(r2.z, m); r2.w += __shfl_xor(r2.w, m);
        r3.x += __shfl_xor(r3.x, m); r3.y += __shfl_xor(r3.y, m);
        r3.z += __shfl_xor(r3.z, m); r3.w += __shfl_xor(r3.w, m);
    }
    if (lane < 4) {   // lane == sub, qi-part == 0
        float* dst = rred + wid * WW + sub * 4;
        *(f32x4*)(dst)      = r0;
        *(f32x4*)(dst + 16) = r1;
        *(f32x4*)(dst + 32) = r2;
        *(f32x4*)(dst + 48) = r3;
    }
    __syncthreads();
    if (t < WW) {
        float s = rred[t];
#pragma unroll
        for (int wv = 1; wv < 8; ++wv) s += rred[wv * WW + t];
        rout[(size_t)b * WW + t] = s;
    }
}

extern "C" void kernel_launch(void* const* d_in, const int* in_sizes, int n_in,
                              void* d_out, int out_size, void* d_ws, size_t ws_size,
                              hipStream_t stream) {
    const float* inputs = (const float*)d_in[0];
    const float* w_pre  = (const float*)d_in[1];
    const float* M      = (const float*)d_in[2];
    const float* W_fc   = (const float*)d_in[3];
    const float* b_fc   = (const float*)d_in[4];

    float* out = (float*)d_out;
    float* r_out = out;                 // B*W floats
    float* w_out = out + BB * WW;       // B*N floats

    k_fused<<<BB, TB, 0, stream>>>(inputs, W_fc, b_fc, w_pre, M, w_out, r_out);
}